// Round 2
// baseline (2586.288 us; speedup 1.0000x reference)
//
#include <hip/hip_runtime.h>
#include <hip/hip_bf16.h>
#include <math.h>

#define DEV_EPS 1e-5f

namespace {
constexpr int B_ = 16, C_ = 256, H_ = 56, W_ = 56, HW_ = H_ * W_;
constexpr int G_ = 16, GC_ = 16, RED_ = 64, KK_ = 49;

// ---------------------------------------------------------------------------
// Fused GEMM + BatchNorm + activation (+ optional skip-add).
// Out[b](M x N) = act( alpha[m] * (A(MxK) @ X[b](K x N)) + beta[m] ) [+ skip]
// ACT: 0 = tanh, 1 = relu, 2 = none + skip add
// 64x64 output tile per block, K-chunks of 16, 256 threads, 4x4 microtile.
// ---------------------------------------------------------------------------
template <int ACT>
__global__ __launch_bounds__(256)
void gemm_bn(const float* __restrict__ A, const float* __restrict__ X,
             const float* __restrict__ bias,
             const float* __restrict__ bng, const float* __restrict__ bnb,
             const float* __restrict__ bnm, const float* __restrict__ bnv,
             const float* __restrict__ skip, float* __restrict__ out,
             int M, int N, int Kd) {
  __shared__ float As[16][68];
  __shared__ float Bs[16][68];
  __shared__ float aS[64], bS[64];

  const int bz = blockIdx.z;
  const int m0 = blockIdx.y * 64, n0 = blockIdx.x * 64;
  const int tid = threadIdx.x;

  if (tid < 64) {
    int m = m0 + tid;
    float sc = bng[m] * rsqrtf(bnv[m] + DEV_EPS);
    aS[tid] = sc;
    bS[tid] = sc * bias[m] + bnb[m] - bnm[m] * sc;
  }

  const float* Xb = X + (size_t)bz * Kd * N;
  const int ty = tid >> 4, tx = tid & 15;
  const int arow = tid >> 2, ak4 = (tid & 3) << 2;
  const int bk = tid >> 4, bn4 = (tid & 15) << 2;

  float acc[4][4] = {};

  for (int k0 = 0; k0 < Kd; k0 += 16) {
    float4 av = *(const float4*)(A + (size_t)(m0 + arow) * Kd + k0 + ak4);
    float4 xv = *(const float4*)(Xb + (size_t)(k0 + bk) * N + n0 + bn4);
    As[ak4 + 0][arow] = av.x;
    As[ak4 + 1][arow] = av.y;
    As[ak4 + 2][arow] = av.z;
    As[ak4 + 3][arow] = av.w;
    *(float4*)&Bs[bk][bn4] = xv;
    __syncthreads();
#pragma unroll
    for (int kk = 0; kk < 16; kk++) {
      float4 a4 = *(const float4*)&As[kk][ty * 4];
      float4 b4 = *(const float4*)&Bs[kk][tx * 4];
      float ar[4] = {a4.x, a4.y, a4.z, a4.w};
      float br[4] = {b4.x, b4.y, b4.z, b4.w};
#pragma unroll
      for (int i = 0; i < 4; i++)
#pragma unroll
        for (int j = 0; j < 4; j++) acc[i][j] += ar[i] * br[j];
    }
    __syncthreads();
  }

#pragma unroll
  for (int i = 0; i < 4; i++) {
    int m = m0 + ty * 4 + i;
    float al = aS[ty * 4 + i], be = bS[ty * 4 + i];
    float vv[4];
#pragma unroll
    for (int j = 0; j < 4; j++) {
      float t = al * acc[i][j] + be;
      if (ACT == 0) t = tanhf(t);
      if (ACT == 1) t = fmaxf(t, 0.f);
      vv[j] = t;
    }
    size_t off = (size_t)bz * M * N + (size_t)m * N + n0 + tx * 4;
    if (ACT == 2) {
      float4 s4 = *(const float4*)(skip + off);
      vv[0] += s4.x; vv[1] += s4.y; vv[2] += s4.z; vv[3] += s4.w;
    }
    *(float4*)(out + off) = make_float4(vv[0], vv[1], vv[2], vv[3]);
  }
}

// ---------------------------------------------------------------------------
// Span GEMM: wd[b, m, n] = span_w(784x64) @ r[b](64x3136) + span_b, bf16 out.
// Same 64x64x16 tiling; M=784 ragged (13 m-tiles, last partially masked).
// ---------------------------------------------------------------------------
__global__ __launch_bounds__(256)
void span_gemm(const float* __restrict__ A, const float* __restrict__ X,
               const float* __restrict__ bias, unsigned short* __restrict__ out) {
  constexpr int M = G_ * KK_;  // 784
  constexpr int N = HW_, Kd = RED_;
  __shared__ float As[16][68];
  __shared__ float Bs[16][68];
  __shared__ float bS[64];

  const int bz = blockIdx.z;
  const int m0 = blockIdx.y * 64, n0 = blockIdx.x * 64;
  const int tid = threadIdx.x;

  if (tid < 64) bS[tid] = bias[min(m0 + tid, M - 1)];

  const float* Xb = X + (size_t)bz * Kd * N;
  const int ty = tid >> 4, tx = tid & 15;
  const int arow = tid >> 2, ak4 = (tid & 3) << 2;
  const int bk = tid >> 4, bn4 = (tid & 15) << 2;
  const int am = min(m0 + arow, M - 1);

  float acc[4][4] = {};

#pragma unroll
  for (int k0 = 0; k0 < Kd; k0 += 16) {
    float4 av = *(const float4*)(A + (size_t)am * Kd + k0 + ak4);
    float4 xv = *(const float4*)(Xb + (size_t)(k0 + bk) * N + n0 + bn4);
    As[ak4 + 0][arow] = av.x;
    As[ak4 + 1][arow] = av.y;
    As[ak4 + 2][arow] = av.z;
    As[ak4 + 3][arow] = av.w;
    *(float4*)&Bs[bk][bn4] = xv;
    __syncthreads();
#pragma unroll
    for (int kk = 0; kk < 16; kk++) {
      float4 a4 = *(const float4*)&As[kk][ty * 4];
      float4 b4 = *(const float4*)&Bs[kk][tx * 4];
      float ar[4] = {a4.x, a4.y, a4.z, a4.w};
      float br[4] = {b4.x, b4.y, b4.z, b4.w};
#pragma unroll
      for (int i = 0; i < 4; i++)
#pragma unroll
        for (int j = 0; j < 4; j++) acc[i][j] += ar[i] * br[j];
    }
    __syncthreads();
  }

#pragma unroll
  for (int i = 0; i < 4; i++) {
    int m = m0 + ty * 4 + i;
    if (m >= M) break;
    float be = bS[ty * 4 + i];
    union { ushort4 u; __hip_bfloat16 h[4]; } cv;
#pragma unroll
    for (int j = 0; j < 4; j++) cv.h[j] = __float2bfloat16(acc[i][j] + be);
    *(ushort4*)(out + (size_t)bz * M * N + (size_t)m * N + n0 + tx * 4) = cv.u;
  }
}

// ---------------------------------------------------------------------------
// Gather: t[b,c,hw] = tanh(bn2( sum_{di,dj} wd[b,g,di*7+dj,hw] * y_patch ))
// Block = (row-tile of 2 rows x 56 cols, group g, batch b).
// LDS: wts 49x112 fp32 (staged from bf16 wd) + patch 16 x (8x62 padded) fp32.
// ---------------------------------------------------------------------------
constexpr int PATCH_STR = 520;  // per-gc y-patch plane: 8 rows * 64 + 8 pad
constexpr int GOFF_WTS = 0;             // 49*112 = 5488 floats
constexpr int GOFF_PATCH = 5488;        // 16*520 = 8320 floats
constexpr int GOFF_A2 = 13808;          // 16
constexpr int GOFF_B2 = 13824;          // 16
constexpr int GSMEM = 13840;            // 55.4 KB -> 2 blocks/CU

__global__ __launch_bounds__(256)
void gather_inv(const float* __restrict__ y, const unsigned short* __restrict__ wd,
                const float* __restrict__ g2, const float* __restrict__ b2,
                const float* __restrict__ m2, const float* __restrict__ v2,
                float* __restrict__ tout) {
  __shared__ float smem[GSMEM];
  float* wts = smem + GOFF_WTS;
  float* patch = smem + GOFF_PATCH;
  float* a2s = smem + GOFF_A2;
  float* b2s = smem + GOFF_B2;

  const int tid = threadIdx.x;
  const int rt = blockIdx.x;  // row tile 0..27
  const int g = blockIdx.y;   // group 0..15
  const int b = blockIdx.z;   // batch 0..15
  const int h0 = rt * 2;
  const int pix0 = h0 * W_;

  // ---- stage wd slice: 49 taps x 112 px, bf16 -> fp32 ----
  {
    const unsigned short* wdp = wd + ((size_t)(b * G_ + g) * KK_) * HW_ + pix0;
    for (int q = tid; q < KK_ * 28; q += 256) {
      int tap = q / 28, p4 = q - tap * 28;
      ushort4 w4 = *(const ushort4*)(wdp + (size_t)tap * HW_ + p4 * 4);
      float4 f4 = make_float4(__uint_as_float((unsigned)w4.x << 16),
                              __uint_as_float((unsigned)w4.y << 16),
                              __uint_as_float((unsigned)w4.z << 16),
                              __uint_as_float((unsigned)w4.w << 16));
      *(float4*)&wts[tap * 112 + p4 * 4] = f4;
    }
    if (tid < 16) {
      int c = g * GC_ + tid;
      float sc = g2[c] * rsqrtf(v2[c] + DEV_EPS);
      a2s[tid] = sc;
      b2s[tid] = b2[c] - m2[c] * sc;
    }
    // ---- stage y patch: 16 gc-planes of 8 rows x 62 cols (zero-padded) ----
    const float* yb = y + ((size_t)b * C_ + g * GC_) * HW_;
    for (int idx = tid; idx < GC_ * 8 * 62; idx += 256) {
      int cc = idx / 496;
      int rem = idx - cc * 496;
      int rr = rem / 62;
      int cw = rem - rr * 62;
      int sr = h0 + rr - 3;
      int sc = cw - 3;
      float val = 0.f;
      if (sr >= 0 && sr < H_ && sc >= 0 && sc < W_)
        val = yb[(size_t)cc * HW_ + sr * W_ + sc];
      patch[cc * PATCH_STR + rr * 64 + cw] = val;
    }
  }
  __syncthreads();

  // ---- 7x7 gather, 2 gc-planes x 4 px per thread ----
  if (tid < 224) {
    const int p4 = tid % 28, gp = tid / 28;  // gp 0..7
    const int pr = p4 / 14, pc0 = (p4 % 14) * 4;
    const int gc0 = gp * 2;
    float acc0[4] = {}, acc1[4] = {};
#pragma unroll
    for (int di = 0; di < 7; di++) {
      int ro0 = gc0 * PATCH_STR + (pr + di) * 64 + pc0;
      int ro1 = ro0 + PATCH_STR;
      float w0[10], w1[10];
      *(float4*)&w0[0] = *(const float4*)&patch[ro0];
      *(float4*)&w0[4] = *(const float4*)&patch[ro0 + 4];
      *(float2*)&w0[8] = *(const float2*)&patch[ro0 + 8];
      *(float4*)&w1[0] = *(const float4*)&patch[ro1];
      *(float4*)&w1[4] = *(const float4*)&patch[ro1 + 4];
      *(float2*)&w1[8] = *(const float2*)&patch[ro1 + 8];
#pragma unroll
      for (int dj = 0; dj < 7; dj++) {
        float4 wt = *(const float4*)&wts[(di * 7 + dj) * 112 + p4 * 4];
        float wtr[4] = {wt.x, wt.y, wt.z, wt.w};
#pragma unroll
        for (int px = 0; px < 4; px++) {
          acc0[px] += wtr[px] * w0[dj + px];
          acc1[px] += wtr[px] * w1[dj + px];
        }
      }
    }
    const int gpix = pix0 + pr * W_ + pc0;
    {
      int c0 = g * GC_ + gc0;
      float al = a2s[gc0], be = b2s[gc0];
      float4 o0 = make_float4(tanhf(al * acc0[0] + be), tanhf(al * acc0[1] + be),
                              tanhf(al * acc0[2] + be), tanhf(al * acc0[3] + be));
      *(float4*)(tout + ((size_t)b * C_ + c0) * HW_ + gpix) = o0;
      al = a2s[gc0 + 1];
      be = b2s[gc0 + 1];
      float4 o1 = make_float4(tanhf(al * acc1[0] + be), tanhf(al * acc1[1] + be),
                              tanhf(al * acc1[2] + be), tanhf(al * acc1[3] + be));
      *(float4*)(tout + ((size_t)b * C_ + c0 + 1) * HW_ + gpix) = o1;
    }
  }
}

}  // namespace

extern "C" void kernel_launch(void* const* d_in, const int* in_sizes, int n_in,
                              void* d_out, int out_size, void* d_ws, size_t ws_size,
                              hipStream_t stream) {
  const float* x = (const float*)d_in[0];
  const float* w1 = (const float*)d_in[1];
  const float* b1 = (const float*)d_in[2];
  const float* bn1g = (const float*)d_in[3];
  const float* bn1b = (const float*)d_in[4];
  const float* bn1m = (const float*)d_in[5];
  const float* bn1v = (const float*)d_in[6];
  const float* red_w = (const float*)d_in[7];
  const float* red_b = (const float*)d_in[8];
  const float* rbg = (const float*)d_in[9];
  const float* rbb = (const float*)d_in[10];
  const float* rbm = (const float*)d_in[11];
  const float* rbv = (const float*)d_in[12];
  const float* span_w = (const float*)d_in[13];
  const float* span_b = (const float*)d_in[14];
  const float* bn2g = (const float*)d_in[15];
  const float* bn2b = (const float*)d_in[16];
  const float* bn2m = (const float*)d_in[17];
  const float* bn2v = (const float*)d_in[18];
  const float* w3 = (const float*)d_in[19];
  const float* b3 = (const float*)d_in[20];
  const float* bn3g = (const float*)d_in[21];
  const float* bn3b = (const float*)d_in[22];
  const float* bn3m = (const float*)d_in[23];
  const float* bn3v = (const float*)d_in[24];

  float* ws = (float*)d_ws;
  float* y = ws;                                     // (B,256,3136) fp32
  float* r = y + (size_t)B_ * C_ * HW_;              // (B,64,3136)  fp32
  float* t = r + (size_t)B_ * RED_ * HW_;            // (B,256,3136) fp32
  unsigned short* wd = (unsigned short*)(t + (size_t)B_ * C_ * HW_);  // (B,784,3136) bf16
  float* out = (float*)d_out;

  dim3 blk(256);
  // y = tanh(bn1(w1 @ x + b1))
  gemm_bn<0><<<dim3(49, 4, 16), blk, 0, stream>>>(
      w1, x, b1, bn1g, bn1b, bn1m, bn1v, nullptr, y, C_, HW_, C_);
  // r = relu(bn_red(red_w @ y + red_b))
  gemm_bn<1><<<dim3(49, 1, 16), blk, 0, stream>>>(
      red_w, y, red_b, rbg, rbb, rbm, rbv, nullptr, r, RED_, HW_, C_);
  // wd = span_w @ r + span_b   (bf16)
  span_gemm<<<dim3(49, 13, 16), blk, 0, stream>>>(span_w, r, span_b, wd);
  // t = tanh(bn2(gather(y, wd)))
  gather_inv<<<dim3(28, 16, 16), blk, 0, stream>>>(
      y, wd, bn2g, bn2b, bn2m, bn2v, t);
  // out = bn3(w3 @ t + b3) + x
  gemm_bn<2><<<dim3(49, 4, 16), blk, 0, stream>>>(
      w3, t, b3, bn3g, bn3b, bn3m, bn3v, x, out, C_, HW_, C_);
}

// Round 3
// 883.037 us; speedup vs baseline: 2.9289x; 2.9289x over previous
//
#include <hip/hip_runtime.h>
#include <hip/hip_bf16.h>
#include <math.h>

#define DEV_EPS 1e-5f

namespace {
constexpr int B_ = 16, C_ = 256, H_ = 56, W_ = 56, HW_ = H_ * W_;
constexpr int G_ = 16, GC_ = 16, RED_ = 64, KK_ = 49;

// ---------------------------------------------------------------------------
// Fused GEMM + BatchNorm + activation (+ optional skip-add).
// Out[b](M x N) = act( alpha[m] * (A(MxK) @ X[b](K x N)) + beta[m] ) [+ skip]
// ACT: 0 = tanh, 1 = relu, 2 = none + skip add
// 64x64 output tile per block, K-chunks of 16, 256 threads, 4x4 microtile.
// NOTE: do NOT unroll the k0 loop — round-2 showed it pushes VGPR to 256 and
// spills accumulators to scratch (6 GB of HBM traffic, 13x slowdown).
// ---------------------------------------------------------------------------
template <int ACT>
__global__ __launch_bounds__(256)
void gemm_bn(const float* __restrict__ A, const float* __restrict__ X,
             const float* __restrict__ bias,
             const float* __restrict__ bng, const float* __restrict__ bnb,
             const float* __restrict__ bnm, const float* __restrict__ bnv,
             const float* __restrict__ skip, float* __restrict__ out,
             int M, int N, int Kd) {
  __shared__ float As[16][68];
  __shared__ float Bs[16][68];
  __shared__ float aS[64], bS[64];

  const int bz = blockIdx.z;
  const int m0 = blockIdx.y * 64, n0 = blockIdx.x * 64;
  const int tid = threadIdx.x;

  if (tid < 64) {
    int m = m0 + tid;
    float sc = bng[m] * rsqrtf(bnv[m] + DEV_EPS);
    aS[tid] = sc;
    bS[tid] = sc * bias[m] + bnb[m] - bnm[m] * sc;
  }

  const float* Xb = X + (size_t)bz * Kd * N;
  const int ty = tid >> 4, tx = tid & 15;
  const int arow = tid >> 2, ak4 = (tid & 3) << 2;
  const int bk = tid >> 4, bn4 = (tid & 15) << 2;

  float acc[4][4] = {};

  for (int k0 = 0; k0 < Kd; k0 += 16) {
    float4 av = *(const float4*)(A + (size_t)(m0 + arow) * Kd + k0 + ak4);
    float4 xv = *(const float4*)(Xb + (size_t)(k0 + bk) * N + n0 + bn4);
    As[ak4 + 0][arow] = av.x;
    As[ak4 + 1][arow] = av.y;
    As[ak4 + 2][arow] = av.z;
    As[ak4 + 3][arow] = av.w;
    *(float4*)&Bs[bk][bn4] = xv;
    __syncthreads();
#pragma unroll
    for (int kk = 0; kk < 16; kk++) {
      float4 a4 = *(const float4*)&As[kk][ty * 4];
      float4 b4 = *(const float4*)&Bs[kk][tx * 4];
      float ar[4] = {a4.x, a4.y, a4.z, a4.w};
      float br[4] = {b4.x, b4.y, b4.z, b4.w};
#pragma unroll
      for (int i = 0; i < 4; i++)
#pragma unroll
        for (int j = 0; j < 4; j++) acc[i][j] += ar[i] * br[j];
    }
    __syncthreads();
  }

#pragma unroll
  for (int i = 0; i < 4; i++) {
    int m = m0 + ty * 4 + i;
    float al = aS[ty * 4 + i], be = bS[ty * 4 + i];
    float vv[4];
#pragma unroll
    for (int j = 0; j < 4; j++) {
      float t = al * acc[i][j] + be;
      if (ACT == 0) t = tanhf(t);
      if (ACT == 1) t = fmaxf(t, 0.f);
      vv[j] = t;
    }
    size_t off = (size_t)bz * M * N + (size_t)m * N + n0 + tx * 4;
    if (ACT == 2) {
      float4 s4 = *(const float4*)(skip + off);
      vv[0] += s4.x; vv[1] += s4.y; vv[2] += s4.z; vv[3] += s4.w;
    }
    *(float4*)(out + off) = make_float4(vv[0], vv[1], vv[2], vv[3]);
  }
}

// ---------------------------------------------------------------------------
// Span GEMM: wd[b, m, n] = span_w(784x64) @ r[b](64x3136) + span_b, bf16 out.
// Structurally identical to gemm_bn (rolled K-loop!); bf16-store epilogue.
// M=784 ragged: 13 m-tiles, last partially masked via clamped row index.
// ---------------------------------------------------------------------------
__global__ __launch_bounds__(256)
void span_gemm(const float* __restrict__ A, const float* __restrict__ X,
               const float* __restrict__ bias, unsigned short* __restrict__ out) {
  constexpr int M = G_ * KK_;  // 784
  constexpr int N = HW_;
  __shared__ float As[16][68];
  __shared__ float Bs[16][68];
  __shared__ float bS[64];

  const int bz = blockIdx.z;
  const int m0 = blockIdx.y * 64, n0 = blockIdx.x * 64;
  const int tid = threadIdx.x;

  if (tid < 64) bS[tid] = bias[min(m0 + tid, M - 1)];

  const float* Xb = X + (size_t)bz * RED_ * N;
  const int ty = tid >> 4, tx = tid & 15;
  const int arow = tid >> 2, ak4 = (tid & 3) << 2;
  const int bk = tid >> 4, bn4 = (tid & 15) << 2;
  const int am = min(m0 + arow, M - 1);

  float acc[4][4] = {};

  for (int k0 = 0; k0 < RED_; k0 += 16) {
    float4 av = *(const float4*)(A + (size_t)am * RED_ + k0 + ak4);
    float4 xv = *(const float4*)(Xb + (size_t)(k0 + bk) * N + n0 + bn4);
    As[ak4 + 0][arow] = av.x;
    As[ak4 + 1][arow] = av.y;
    As[ak4 + 2][arow] = av.z;
    As[ak4 + 3][arow] = av.w;
    *(float4*)&Bs[bk][bn4] = xv;
    __syncthreads();
#pragma unroll
    for (int kk = 0; kk < 16; kk++) {
      float4 a4 = *(const float4*)&As[kk][ty * 4];
      float4 b4 = *(const float4*)&Bs[kk][tx * 4];
      float ar[4] = {a4.x, a4.y, a4.z, a4.w};
      float br[4] = {b4.x, b4.y, b4.z, b4.w};
#pragma unroll
      for (int i = 0; i < 4; i++)
#pragma unroll
        for (int j = 0; j < 4; j++) acc[i][j] += ar[i] * br[j];
    }
    __syncthreads();
  }

#pragma unroll
  for (int i = 0; i < 4; i++) {
    int m = m0 + ty * 4 + i;
    if (m >= M) break;
    float be = bS[ty * 4 + i];
    union { ushort4 u; unsigned short s[4]; } cv;
#pragma unroll
    for (int j = 0; j < 4; j++) {
      float t = acc[i][j] + be;
      unsigned u = __float_as_uint(t);
      // round-to-nearest-even bf16
      u += 0x7fff + ((u >> 16) & 1);
      cv.s[j] = (unsigned short)(u >> 16);
    }
    *(ushort4*)(out + (size_t)bz * M * N + (size_t)m * N + n0 + tx * 4) = cv.u;
  }
}

// ---------------------------------------------------------------------------
// Gather: t[b,c,hw] = tanh(bn2( sum_{di,dj} wd[b,g,di*7+dj,hw] * y_patch ))
// Block = (row-tile of 2 rows x 56 cols, group g, batch b).
// LDS: wts 49x112 fp32 (staged from bf16 wd) + patch 16 x (8x62 padded) fp32.
// ---------------------------------------------------------------------------
constexpr int PATCH_STR = 520;  // per-gc y-patch plane: 8 rows * 64 + 8 pad
constexpr int GOFF_WTS = 0;             // 49*112 = 5488 floats
constexpr int GOFF_PATCH = 5488;        // 16*520 = 8320 floats
constexpr int GOFF_A2 = 13808;          // 16
constexpr int GOFF_B2 = 13824;          // 16
constexpr int GSMEM = 13840;            // 55.4 KB -> 2 blocks/CU

__global__ __launch_bounds__(256)
void gather_inv(const float* __restrict__ y, const unsigned short* __restrict__ wd,
                const float* __restrict__ g2, const float* __restrict__ b2,
                const float* __restrict__ m2, const float* __restrict__ v2,
                float* __restrict__ tout) {
  __shared__ float smem[GSMEM];
  float* wts = smem + GOFF_WTS;
  float* patch = smem + GOFF_PATCH;
  float* a2s = smem + GOFF_A2;
  float* b2s = smem + GOFF_B2;

  const int tid = threadIdx.x;
  const int rt = blockIdx.x;  // row tile 0..27
  const int g = blockIdx.y;   // group 0..15
  const int b = blockIdx.z;   // batch 0..15
  const int h0 = rt * 2;
  const int pix0 = h0 * W_;

  // ---- stage wd slice: 49 taps x 112 px, bf16 -> fp32 ----
  {
    const unsigned short* wdp = wd + ((size_t)(b * G_ + g) * KK_) * HW_ + pix0;
    for (int q = tid; q < KK_ * 28; q += 256) {
      int tap = q / 28, p4 = q - tap * 28;
      ushort4 w4 = *(const ushort4*)(wdp + (size_t)tap * HW_ + p4 * 4);
      float4 f4 = make_float4(__uint_as_float((unsigned)w4.x << 16),
                              __uint_as_float((unsigned)w4.y << 16),
                              __uint_as_float((unsigned)w4.z << 16),
                              __uint_as_float((unsigned)w4.w << 16));
      *(float4*)&wts[tap * 112 + p4 * 4] = f4;
    }
    if (tid < 16) {
      int c = g * GC_ + tid;
      float sc = g2[c] * rsqrtf(v2[c] + DEV_EPS);
      a2s[tid] = sc;
      b2s[tid] = b2[c] - m2[c] * sc;
    }
    // ---- stage y patch: 16 gc-planes of 8 rows x 62 cols (zero-padded) ----
    const float* yb = y + ((size_t)b * C_ + g * GC_) * HW_;
    for (int idx = tid; idx < GC_ * 8 * 62; idx += 256) {
      int cc = idx / 496;
      int rem = idx - cc * 496;
      int rr = rem / 62;
      int cw = rem - rr * 62;
      int sr = h0 + rr - 3;
      int sc = cw - 3;
      float val = 0.f;
      if (sr >= 0 && sr < H_ && sc >= 0 && sc < W_)
        val = yb[(size_t)cc * HW_ + sr * W_ + sc];
      patch[cc * PATCH_STR + rr * 64 + cw] = val;
    }
  }
  __syncthreads();

  // ---- 7x7 gather, 2 gc-planes x 4 px per thread ----
  if (tid < 224) {
    const int p4 = tid % 28, gp = tid / 28;  // gp 0..7
    const int pr = p4 / 14, pc0 = (p4 % 14) * 4;
    const int gc0 = gp * 2;
    float acc0[4] = {}, acc1[4] = {};
#pragma unroll
    for (int di = 0; di < 7; di++) {
      int ro0 = gc0 * PATCH_STR + (pr + di) * 64 + pc0;
      int ro1 = ro0 + PATCH_STR;
      float w0[10], w1[10];
      *(float4*)&w0[0] = *(const float4*)&patch[ro0];
      *(float4*)&w0[4] = *(const float4*)&patch[ro0 + 4];
      *(float2*)&w0[8] = *(const float2*)&patch[ro0 + 8];
      *(float4*)&w1[0] = *(const float4*)&patch[ro1];
      *(float4*)&w1[4] = *(const float4*)&patch[ro1 + 4];
      *(float2*)&w1[8] = *(const float2*)&patch[ro1 + 8];
#pragma unroll
      for (int dj = 0; dj < 7; dj++) {
        float4 wt = *(const float4*)&wts[(di * 7 + dj) * 112 + p4 * 4];
        float wtr[4] = {wt.x, wt.y, wt.z, wt.w};
#pragma unroll
        for (int px = 0; px < 4; px++) {
          acc0[px] += wtr[px] * w0[dj + px];
          acc1[px] += wtr[px] * w1[dj + px];
        }
      }
    }
    const int gpix = pix0 + pr * W_ + pc0;
    {
      int c0 = g * GC_ + gc0;
      float al = a2s[gc0], be = b2s[gc0];
      float4 o0 = make_float4(tanhf(al * acc0[0] + be), tanhf(al * acc0[1] + be),
                              tanhf(al * acc0[2] + be), tanhf(al * acc0[3] + be));
      *(float4*)(tout + ((size_t)b * C_ + c0) * HW_ + gpix) = o0;
      al = a2s[gc0 + 1];
      be = b2s[gc0 + 1];
      float4 o1 = make_float4(tanhf(al * acc1[0] + be), tanhf(al * acc1[1] + be),
                              tanhf(al * acc1[2] + be), tanhf(al * acc1[3] + be));
      *(float4*)(tout + ((size_t)b * C_ + c0 + 1) * HW_ + gpix) = o1;
    }
  }
}

}  // namespace

extern "C" void kernel_launch(void* const* d_in, const int* in_sizes, int n_in,
                              void* d_out, int out_size, void* d_ws, size_t ws_size,
                              hipStream_t stream) {
  const float* x = (const float*)d_in[0];
  const float* w1 = (const float*)d_in[1];
  const float* b1 = (const float*)d_in[2];
  const float* bn1g = (const float*)d_in[3];
  const float* bn1b = (const float*)d_in[4];
  const float* bn1m = (const float*)d_in[5];
  const float* bn1v = (const float*)d_in[6];
  const float* red_w = (const float*)d_in[7];
  const float* red_b = (const float*)d_in[8];
  const float* rbg = (const float*)d_in[9];
  const float* rbb = (const float*)d_in[10];
  const float* rbm = (const float*)d_in[11];
  const float* rbv = (const float*)d_in[12];
  const float* span_w = (const float*)d_in[13];
  const float* span_b = (const float*)d_in[14];
  const float* bn2g = (const float*)d_in[15];
  const float* bn2b = (const float*)d_in[16];
  const float* bn2m = (const float*)d_in[17];
  const float* bn2v = (const float*)d_in[18];
  const float* w3 = (const float*)d_in[19];
  const float* b3 = (const float*)d_in[20];
  const float* bn3g = (const float*)d_in[21];
  const float* bn3b = (const float*)d_in[22];
  const float* bn3m = (const float*)d_in[23];
  const float* bn3v = (const float*)d_in[24];

  float* ws = (float*)d_ws;
  float* y = ws;                                     // (B,256,3136) fp32
  float* r = y + (size_t)B_ * C_ * HW_;              // (B,64,3136)  fp32
  float* t = r + (size_t)B_ * RED_ * HW_;            // (B,256,3136) fp32
  unsigned short* wd = (unsigned short*)(t + (size_t)B_ * C_ * HW_);  // (B,784,3136) bf16
  float* out = (float*)d_out;

  dim3 blk(256);
  // y = tanh(bn1(w1 @ x + b1))
  gemm_bn<0><<<dim3(49, 4, 16), blk, 0, stream>>>(
      w1, x, b1, bn1g, bn1b, bn1m, bn1v, nullptr, y, C_, HW_, C_);
  // r = relu(bn_red(red_w @ y + red_b))
  gemm_bn<1><<<dim3(49, 1, 16), blk, 0, stream>>>(
      red_w, y, red_b, rbg, rbb, rbm, rbv, nullptr, r, RED_, HW_, C_);
  // wd = span_w @ r + span_b   (bf16)
  span_gemm<<<dim3(49, 13, 16), blk, 0, stream>>>(span_w, r, span_b, wd);
  // t = tanh(bn2(gather(y, wd)))
  gather_inv<<<dim3(28, 16, 16), blk, 0, stream>>>(
      y, wd, bn2g, bn2b, bn2m, bn2v, t);
  // out = bn3(w3 @ t + b3) + x
  gemm_bn<2><<<dim3(49, 4, 16), blk, 0, stream>>>(
      w3, t, b3, bn3g, bn3b, bn3m, bn3v, x, out, C_, HW_, C_);
}

// Round 4
// 567.063 us; speedup vs baseline: 4.5608x; 1.5572x over previous
//
#include <hip/hip_runtime.h>
#include <hip/hip_bf16.h>
#include <math.h>

#define DEV_EPS 1e-5f

namespace {
constexpr int B_ = 16, C_ = 256, H_ = 56, W_ = 56, HW_ = H_ * W_;
constexpr int G_ = 16, GC_ = 16, RED_ = 64, KK_ = 49;

// ---------------------------------------------------------------------------
// Fused GEMM + BatchNorm + activation (+ optional skip-add).
// ACT: 0 = tanh, 1 = relu, 2 = none + skip add
// 64x64 tile, K-chunks of 16, 256 threads, 4x4 microtile.
// NOTE: do NOT unroll the k0 loop — round-2 showed it pushes VGPR to 256 and
// spills accumulators to scratch (6 GB of HBM traffic, 13x slowdown).
// ---------------------------------------------------------------------------
template <int ACT>
__global__ __launch_bounds__(256)
void gemm_bn(const float* __restrict__ A, const float* __restrict__ X,
             const float* __restrict__ bias,
             const float* __restrict__ bng, const float* __restrict__ bnb,
             const float* __restrict__ bnm, const float* __restrict__ bnv,
             const float* __restrict__ skip, float* __restrict__ out,
             int M, int N, int Kd) {
  __shared__ float As[16][68];
  __shared__ float Bs[16][68];
  __shared__ float aS[64], bS[64];

  const int bz = blockIdx.z;
  const int m0 = blockIdx.y * 64, n0 = blockIdx.x * 64;
  const int tid = threadIdx.x;

  if (tid < 64) {
    int m = m0 + tid;
    float sc = bng[m] * rsqrtf(bnv[m] + DEV_EPS);
    aS[tid] = sc;
    bS[tid] = sc * bias[m] + bnb[m] - bnm[m] * sc;
  }

  const float* Xb = X + (size_t)bz * Kd * N;
  const int ty = tid >> 4, tx = tid & 15;
  const int arow = tid >> 2, ak4 = (tid & 3) << 2;
  const int bk = tid >> 4, bn4 = (tid & 15) << 2;

  float acc[4][4] = {};

  for (int k0 = 0; k0 < Kd; k0 += 16) {
    float4 av = *(const float4*)(A + (size_t)(m0 + arow) * Kd + k0 + ak4);
    float4 xv = *(const float4*)(Xb + (size_t)(k0 + bk) * N + n0 + bn4);
    As[ak4 + 0][arow] = av.x;
    As[ak4 + 1][arow] = av.y;
    As[ak4 + 2][arow] = av.z;
    As[ak4 + 3][arow] = av.w;
    *(float4*)&Bs[bk][bn4] = xv;
    __syncthreads();
#pragma unroll
    for (int kk = 0; kk < 16; kk++) {
      float4 a4 = *(const float4*)&As[kk][ty * 4];
      float4 b4 = *(const float4*)&Bs[kk][tx * 4];
      float ar[4] = {a4.x, a4.y, a4.z, a4.w};
      float br[4] = {b4.x, b4.y, b4.z, b4.w};
#pragma unroll
      for (int i = 0; i < 4; i++)
#pragma unroll
        for (int j = 0; j < 4; j++) acc[i][j] += ar[i] * br[j];
    }
    __syncthreads();
  }

#pragma unroll
  for (int i = 0; i < 4; i++) {
    int m = m0 + ty * 4 + i;
    float al = aS[ty * 4 + i], be = bS[ty * 4 + i];
    float vv[4];
#pragma unroll
    for (int j = 0; j < 4; j++) {
      float t = al * acc[i][j] + be;
      if (ACT == 0) t = tanhf(t);
      if (ACT == 1) t = fmaxf(t, 0.f);
      vv[j] = t;
    }
    size_t off = (size_t)bz * M * N + (size_t)m * N + n0 + tx * 4;
    if (ACT == 2) {
      float4 s4 = *(const float4*)(skip + off);
      vv[0] += s4.x; vv[1] += s4.y; vv[2] += s4.z; vv[3] += s4.w;
    }
    *(float4*)(out + off) = make_float4(vv[0], vv[1], vv[2], vv[3]);
  }
}

// ---------------------------------------------------------------------------
// Span GEMM: wd[b, m, n] = span_w(784x64) @ r[b](64x3136) + span_b, bf16 out.
// Rolled K-loop (see spill note above); bf16 RNE store epilogue.
// ---------------------------------------------------------------------------
__global__ __launch_bounds__(256)
void span_gemm(const float* __restrict__ A, const float* __restrict__ X,
               const float* __restrict__ bias, unsigned short* __restrict__ out) {
  constexpr int M = G_ * KK_;  // 784
  constexpr int N = HW_;
  __shared__ float As[16][68];
  __shared__ float Bs[16][68];
  __shared__ float bS[64];

  const int bz = blockIdx.z;
  const int m0 = blockIdx.y * 64, n0 = blockIdx.x * 64;
  const int tid = threadIdx.x;

  if (tid < 64) bS[tid] = bias[min(m0 + tid, M - 1)];

  const float* Xb = X + (size_t)bz * RED_ * N;
  const int ty = tid >> 4, tx = tid & 15;
  const int arow = tid >> 2, ak4 = (tid & 3) << 2;
  const int bk = tid >> 4, bn4 = (tid & 15) << 2;
  const int am = min(m0 + arow, M - 1);

  float acc[4][4] = {};

  for (int k0 = 0; k0 < RED_; k0 += 16) {
    float4 av = *(const float4*)(A + (size_t)am * RED_ + k0 + ak4);
    float4 xv = *(const float4*)(Xb + (size_t)(k0 + bk) * N + n0 + bn4);
    As[ak4 + 0][arow] = av.x;
    As[ak4 + 1][arow] = av.y;
    As[ak4 + 2][arow] = av.z;
    As[ak4 + 3][arow] = av.w;
    *(float4*)&Bs[bk][bn4] = xv;
    __syncthreads();
#pragma unroll
    for (int kk = 0; kk < 16; kk++) {
      float4 a4 = *(const float4*)&As[kk][ty * 4];
      float4 b4 = *(const float4*)&Bs[kk][tx * 4];
      float ar[4] = {a4.x, a4.y, a4.z, a4.w};
      float br[4] = {b4.x, b4.y, b4.z, b4.w};
#pragma unroll
      for (int i = 0; i < 4; i++)
#pragma unroll
        for (int j = 0; j < 4; j++) acc[i][j] += ar[i] * br[j];
    }
    __syncthreads();
  }

#pragma unroll
  for (int i = 0; i < 4; i++) {
    int m = m0 + ty * 4 + i;
    if (m >= M) break;
    float be = bS[ty * 4 + i];
    union { ushort4 u; unsigned short s[4]; } cv;
#pragma unroll
    for (int j = 0; j < 4; j++) {
      float t = acc[i][j] + be;
      unsigned u = __float_as_uint(t);
      u += 0x7fff + ((u >> 16) & 1);  // RNE bf16
      cv.s[j] = (unsigned short)(u >> 16);
    }
    *(ushort4*)(out + (size_t)bz * M * N + (size_t)m * N + n0 + tx * 4) = cv.u;
  }
}

// ---------------------------------------------------------------------------
// Gather v3: t = tanh(bn2( sum_tap wd[tap,px] * y[gc, px+off(tap)] )).
// Block = (b, g, 4-row stripe).  Grid 14 x 16 x 16.
// LDS: wts = raw bf16 49 x 224px (stride 232 shorts; 16 gc-lanes broadcast
//      the same address -> conflict-free), patch = fp32 16gc x 10r x 64c
//      (gc stride 644 == 4 mod 32 -> only free 2-way aliasing).
// Items: 56 px4-strips x 16 gc = 896, looped 3.5x over 256 threads.
// One barrier; long register-resident compute phase for latency hiding.
// ---------------------------------------------------------------------------
constexpr int P_GC_STR = 644;   // floats: 10 rows * 64 + 4 pad
constexpr int W_TAP_STR = 232;  // ushorts: 224 px + 8 pad (16B-aligned rows)

__global__ __launch_bounds__(256)
void gather_inv(const float* __restrict__ y, const unsigned short* __restrict__ wd,
                const float* __restrict__ g2, const float* __restrict__ b2,
                const float* __restrict__ m2, const float* __restrict__ v2,
                float* __restrict__ tout) {
  __shared__ float patch[16 * P_GC_STR];       // 41216 B
  __shared__ unsigned short wts[49 * W_TAP_STR];  // 22736 B
  __shared__ float a2s[16], b2s[16];

  const int tid = threadIdx.x;
  const int st = blockIdx.x;  // stripe 0..13
  const int g = blockIdx.y;
  const int b = blockIdx.z;
  const int h0 = st * 4;

  // ---- stage wts: 49 taps x 224 contiguous stripe pixels (bf16 raw) ----
  {
    const unsigned short* wdp = wd + ((size_t)(b * G_ + g) * KK_) * HW_ + h0 * W_;
    for (int idx = tid; idx < KK_ * 28; idx += 256) {
      int tap = idx / 28, ch = idx - tap * 28;
      uint4 v = *(const uint4*)(wdp + (size_t)tap * HW_ + ch * 8);
      *(uint4*)&wts[tap * W_TAP_STR + ch * 8] = v;
    }
    if (tid < 16) {
      int c = g * GC_ + tid;
      float sc = g2[c] * rsqrtf(v2[c] + DEV_EPS);
      a2s[tid] = sc;
      b2s[tid] = b2[c] - m2[c] * sc;
    }
    // ---- stage patch: per-gc team of 16 threads, 10 rows x 62 cols ----
    const int team = tid >> 4, slot = tid & 15;
    const float* yb = y + ((size_t)b * C_ + g * GC_ + team) * HW_;
    float* pp = patch + team * P_GC_STR;
    for (int e = slot; e < 10 * 62; e += 16) {
      int row = e / 62, cw = e - row * 62;
      int sr = h0 + row - 3, sc = cw - 3;
      float v = 0.f;
      if (sr >= 0 && sr < H_ && sc >= 0 && sc < W_) v = yb[sr * W_ + sc];
      pp[row * 64 + cw] = v;
    }
  }
  __syncthreads();

  // ---- compute: item = (px4 strip s, gc); 196 FMA per item ----
#pragma unroll 1
  for (int it = 0; it < 4; ++it) {
    int item = tid + it * 256;
    if (item >= 56 * 16) break;
    const int gc = item & 15, s = item >> 4;
    const int r0 = s / 14, c0 = (s - r0 * 14) * 4;
    const float* prow0 = patch + gc * P_GC_STR + r0 * 64 + c0;
    const unsigned short* wp = wts + (r0 * 56 + c0);
    float acc0 = 0.f, acc1 = 0.f, acc2 = 0.f, acc3 = 0.f;
#pragma unroll
    for (int di = 0; di < 7; ++di) {
      const float* pr = prow0 + di * 64;
      float4 pa = *(const float4*)pr;
      float4 pb = *(const float4*)(pr + 4);
      float4 pc2 = *(const float4*)(pr + 8);
      float pf[12] = {pa.x, pa.y, pa.z, pa.w, pb.x, pb.y, pb.z, pb.w,
                      pc2.x, pc2.y, pc2.z, pc2.w};
#pragma unroll
      for (int dj = 0; dj < 7; ++dj) {
        ushort4 wv = *(const ushort4*)(wp + (di * 7 + dj) * W_TAP_STR);
        float w0 = __uint_as_float((unsigned)wv.x << 16);
        float w1 = __uint_as_float((unsigned)wv.y << 16);
        float w2 = __uint_as_float((unsigned)wv.z << 16);
        float w3 = __uint_as_float((unsigned)wv.w << 16);
        acc0 += w0 * pf[dj + 0];
        acc1 += w1 * pf[dj + 1];
        acc2 += w2 * pf[dj + 2];
        acc3 += w3 * pf[dj + 3];
      }
    }
    const float al = a2s[gc], be = b2s[gc];
    float4 o = make_float4(tanhf(al * acc0 + be), tanhf(al * acc1 + be),
                           tanhf(al * acc2 + be), tanhf(al * acc3 + be));
    *(float4*)(tout + ((size_t)b * C_ + g * GC_ + gc) * HW_ + (h0 + r0) * W_ + c0) = o;
  }
}

}  // namespace

extern "C" void kernel_launch(void* const* d_in, const int* in_sizes, int n_in,
                              void* d_out, int out_size, void* d_ws, size_t ws_size,
                              hipStream_t stream) {
  const float* x = (const float*)d_in[0];
  const float* w1 = (const float*)d_in[1];
  const float* b1 = (const float*)d_in[2];
  const float* bn1g = (const float*)d_in[3];
  const float* bn1b = (const float*)d_in[4];
  const float* bn1m = (const float*)d_in[5];
  const float* bn1v = (const float*)d_in[6];
  const float* red_w = (const float*)d_in[7];
  const float* red_b = (const float*)d_in[8];
  const float* rbg = (const float*)d_in[9];
  const float* rbb = (const float*)d_in[10];
  const float* rbm = (const float*)d_in[11];
  const float* rbv = (const float*)d_in[12];
  const float* span_w = (const float*)d_in[13];
  const float* span_b = (const float*)d_in[14];
  const float* bn2g = (const float*)d_in[15];
  const float* bn2b = (const float*)d_in[16];
  const float* bn2m = (const float*)d_in[17];
  const float* bn2v = (const float*)d_in[18];
  const float* w3 = (const float*)d_in[19];
  const float* b3 = (const float*)d_in[20];
  const float* bn3g = (const float*)d_in[21];
  const float* bn3b = (const float*)d_in[22];
  const float* bn3m = (const float*)d_in[23];
  const float* bn3v = (const float*)d_in[24];

  float* ws = (float*)d_ws;
  float* y = ws;                                     // (B,256,3136) fp32
  float* r = y + (size_t)B_ * C_ * HW_;              // (B,64,3136)  fp32
  float* t = r + (size_t)B_ * RED_ * HW_;            // (B,256,3136) fp32
  unsigned short* wd = (unsigned short*)(t + (size_t)B_ * C_ * HW_);  // (B,784,3136) bf16
  float* out = (float*)d_out;

  dim3 blk(256);
  // y = tanh(bn1(w1 @ x + b1))
  gemm_bn<0><<<dim3(49, 4, 16), blk, 0, stream>>>(
      w1, x, b1, bn1g, bn1b, bn1m, bn1v, nullptr, y, C_, HW_, C_);
  // r = relu(bn_red(red_w @ y + red_b))
  gemm_bn<1><<<dim3(49, 1, 16), blk, 0, stream>>>(
      red_w, y, red_b, rbg, rbb, rbm, rbv, nullptr, r, RED_, HW_, C_);
  // wd = span_w @ r + span_b   (bf16)
  span_gemm<<<dim3(49, 13, 16), blk, 0, stream>>>(span_w, r, span_b, wd);
  // t = tanh(bn2(gather(y, wd)))
  gather_inv<<<dim3(14, 16, 16), blk, 0, stream>>>(
      y, wd, bn2g, bn2b, bn2m, bn2v, t);
  // out = bn3(w3 @ t + b3) + x
  gemm_bn<2><<<dim3(49, 4, 16), blk, 0, stream>>>(
      w3, t, b3, bn3g, bn3b, bn3m, bn3v, x, out, C_, HW_, C_);
}

// Round 5
// 389.132 us; speedup vs baseline: 6.6463x; 1.4573x over previous
//
#include <hip/hip_runtime.h>
#include <math.h>

#define DEV_EPS 1e-5f

namespace {
constexpr int B_ = 16, C_ = 256, H_ = 56, W_ = 56, HW_ = H_ * W_;
constexpr int G_ = 16, GC_ = 16, RED_ = 64, KK_ = 49;
constexpr int NTOT = B_ * HW_;  // 50176 flattened (batch, pixel)

typedef __attribute__((ext_vector_type(8))) short short8;
typedef __attribute__((ext_vector_type(4))) float f32x4;

__device__ __forceinline__ unsigned short bf16r(float f) {
  unsigned u = __float_as_uint(f);
  u += 0x7fff + ((u >> 16) & 1);  // RNE
  return (unsigned short)(u >> 16);
}
__device__ __forceinline__ float bf2f(unsigned short s) {
  return __uint_as_float((unsigned)s << 16);
}

// async global->LDS, 16B per lane. LDS dest is wave-uniform base + lane*16
// (m104: no per-lane LDS scatter) — so any swizzle goes on the GLOBAL address.
__device__ __forceinline__ void gl_lds16(const void* g, void* l) {
  __builtin_amdgcn_global_load_lds(
      (const __attribute__((address_space(1))) unsigned int*)g,
      (__attribute__((address_space(3))) unsigned int*)l, 16, 0, 0);
}

// ---------------------------------------------------------------------------
// MFMA GEMM: D[m][n] = sum_k Wt[m][k] * Act[n][k]   (both bf16, k-contiguous)
// Block = 256 threads = 4 waves; wave tile 64x64; BM=WM*64, BN=WN*64, BK=64.
// LDS tiles [row][64k] bf16, 128B rows; global chunk q^(row&7) XOR-swizzle so
// frag ds_read_b128 is 2-way-only (free, m136).
// EPI: 0 = tanh(bn)->act_T bf16, 1 = relu(bn)->act_T bf16,
//      2 = +bias -> planar bf16 [M][NTOT] (span, ragged M),
//      3 = bn + x skip -> planar fp32 [b][C][HW] (final out)
// ---------------------------------------------------------------------------
template <int WM, int WN, int KD, int EPI>
__global__ __launch_bounds__(256)
void mfma_gemm(const unsigned short* __restrict__ A,   // [M][KD] bf16
               const unsigned short* __restrict__ Act, // [NTOT][KD] bf16
               const float* __restrict__ p0,
               const float* __restrict__ bg, const float* __restrict__ bb,
               const float* __restrict__ bm, const float* __restrict__ bv,
               const float* __restrict__ xskip, void* __restrict__ outp,
               int M) {
  constexpr int BM = WM * 64, BN = WN * 64;
  __shared__ unsigned short At[BM * 64];
  __shared__ unsigned short Bt[BN * 64];
  __shared__ float aS[BM], bS[BM];

  const int tid = threadIdx.x;
  const int n0 = blockIdx.x * BN, m0 = blockIdx.y * BM;
  const int wave = tid >> 6, lane = tid & 63;
  const int wm = (WM == 2) ? (wave >> 1) : 0;
  const int wn = (WM == 2) ? (wave & 1) : wave;

  if (tid < BM) {
    int m = min(m0 + tid, M - 1);
    if (EPI == 2) {
      aS[tid] = 0.f;
      bS[tid] = p0[m];
    } else {
      float sc = bg[m] * rsqrtf(bv[m] + DEV_EPS);
      aS[tid] = sc;
      bS[tid] = sc * p0[m] + bb[m] - bm[m] * sc;
    }
  }

  f32x4 acc[4][4];
#pragma unroll
  for (int i = 0; i < 4; ++i)
#pragma unroll
    for (int j = 0; j < 4; ++j)
#pragma unroll
      for (int e = 0; e < 4; ++e) acc[i][j][e] = 0.f;

  const int lq = lane & 7;          // chunk slot within a row-octet
  const int lr8 = lane >> 3;        // row within octet group
  const int quad = lane >> 4, ln = lane & 15;

#pragma unroll 1
  for (int kt = 0; kt < KD / 64; ++kt) {
    __syncthreads();  // protect LDS from previous iteration's readers
    // stage A: BM rows x 64k; one instr = 8 rows (1KB)
#pragma unroll
    for (int t = 0; t < BM / 32; ++t) {
      int inst = wave * (BM / 32) + t;
      int row = inst * 8 + lr8;
      int mrow = min(m0 + row, M - 1);
      int qs = lq ^ (row & 7);
      gl_lds16(A + (size_t)mrow * KD + kt * 64 + qs * 8, &At[inst * 512]);
    }
    // stage B (activations)
#pragma unroll
    for (int t = 0; t < BN / 32; ++t) {
      int inst = wave * (BN / 32) + t;
      int row = inst * 8 + lr8;
      int qs = lq ^ (row & 7);
      gl_lds16(Act + (size_t)(n0 + row) * KD + kt * 64 + qs * 8, &Bt[inst * 512]);
    }
    __syncthreads();  // barrier drains vmcnt -> LDS tiles complete

#pragma unroll
    for (int s = 0; s < 2; ++s) {
      const int c = s * 4 + quad;
      short8 af[4], bf[4];
#pragma unroll
      for (int i = 0; i < 4; ++i) {
        int r = wm * 64 + i * 16 + ln;
        af[i] = *(const short8*)&At[r * 64 + (c ^ (r & 7)) * 8];
      }
#pragma unroll
      for (int j = 0; j < 4; ++j) {
        int r = wn * 64 + j * 16 + ln;
        bf[j] = *(const short8*)&Bt[r * 64 + (c ^ (r & 7)) * 8];
      }
#pragma unroll
      for (int i = 0; i < 4; ++i)
#pragma unroll
        for (int j = 0; j < 4; ++j)
          acc[i][j] = __builtin_amdgcn_mfma_f32_16x16x32_bf16(af[i], bf[j],
                                                              acc[i][j], 0, 0, 0);
    }
  }

  // epilogue: D col = lane&15 (n), row = quad*4 + reg (m)  [m89-verified]
#pragma unroll
  for (int i = 0; i < 4; ++i) {
    const int mloc = wm * 64 + i * 16 + quad * 4;
#pragma unroll
    for (int j = 0; j < 4; ++j) {
      const int np = n0 + wn * 64 + j * 16 + ln;
      if (EPI == 0 || EPI == 1) {
        ushort4 pk;
        unsigned short* pp = (unsigned short*)&pk;
#pragma unroll
        for (int r = 0; r < 4; ++r) {
          float v = aS[mloc + r] * acc[i][j][r] + bS[mloc + r];
          v = (EPI == 0) ? tanhf(v) : fmaxf(v, 0.f);
          pp[r] = bf16r(v);
        }
        *(ushort4*)((unsigned short*)outp + (size_t)np * M + m0 + mloc) = pk;
      } else if (EPI == 2) {
#pragma unroll
        for (int r = 0; r < 4; ++r) {
          int m = m0 + mloc + r;
          if (m < M)
            ((unsigned short*)outp)[(size_t)m * NTOT + np] =
                bf16r(acc[i][j][r] + bS[mloc + r]);
        }
      } else {
        int b = np / HW_, hw = np - b * HW_;
        size_t base = ((size_t)b * C_ + m0 + mloc) * HW_ + hw;
#pragma unroll
        for (int r = 0; r < 4; ++r) {
          size_t o = base + (size_t)r * HW_;
          ((float*)outp)[o] =
              aS[mloc + r] * acc[i][j][r] + bS[mloc + r] + xskip[o];
        }
      }
    }
  }
}

// ---------------------------------------------------------------------------
// x (planar fp32) -> x_T (bf16, [b*HW+px][c])  via LDS transpose.
// Block: 128 pixels x 256 ch in 4 passes of 64 ch. Grid 392.
// ---------------------------------------------------------------------------
__global__ __launch_bounds__(256)
void transpose_x(const float* __restrict__ x, unsigned short* __restrict__ xT) {
  __shared__ unsigned short tile[128 * 72];  // stride 72 (144B, 16B-aligned)
  const int tid = threadIdx.x;
  const int px0 = blockIdx.x * 128;
  for (int p = 0; p < 4; ++p) {
    if (p) __syncthreads();
#pragma unroll
    for (int e = 0; e < 32; ++e) {
      int flat = e * 256 + tid;
      int cl = flat >> 7, pxl = flat & 127;
      int px = px0 + pxl;
      int b = px / HW_, hw = px - b * HW_;
      tile[pxl * 72 + cl] = bf16r(x[((size_t)b * C_ + p * 64 + cl) * HW_ + hw]);
    }
    __syncthreads();
    int px = tid >> 1, half = tid & 1;
    const unsigned short* src = &tile[px * 72 + half * 32];
    unsigned short* dst = &xT[(size_t)(px0 + px) * C_ + p * 64 + half * 32];
    *(uint4*)(dst + 0) = *(const uint4*)(src + 0);
    *(uint4*)(dst + 8) = *(const uint4*)(src + 8);
    *(uint4*)(dst + 16) = *(const uint4*)(src + 16);
    *(uint4*)(dst + 24) = *(const uint4*)(src + 24);
  }
}

// weights fp32 -> bf16 (all four mats)
__global__ __launch_bounds__(256)
void wconv(const float* __restrict__ w1, const float* __restrict__ rw,
           const float* __restrict__ sw, const float* __restrict__ w3,
           unsigned short* __restrict__ o1, unsigned short* __restrict__ orw,
           unsigned short* __restrict__ osw, unsigned short* __restrict__ ow3) {
  int i = blockIdx.x * 256 + threadIdx.x;
  if (i < 65536) o1[i] = bf16r(w1[i]);
  if (i < 16384) orw[i] = bf16r(rw[i]);
  if (i < 50176) osw[i] = bf16r(sw[i]);
  if (i < 65536) ow3[i] = bf16r(w3[i]);
}

// ---------------------------------------------------------------------------
// Gather v4: inputs y_T (bf16 [pix][c]) + wd (bf16 planar [784][NTOT]);
// output t_T (bf16 [pix][c]) via LDS bounce. Compute phase = round-4 (proven).
// ---------------------------------------------------------------------------
constexpr int P_GC_STR = 644;   // fp32 plane: 10r*64c + 4 pad
constexpr int W_TAP_STR = 232;  // ushort: 224 px + 8 pad

__global__ __launch_bounds__(256)
void gather_inv(const unsigned short* __restrict__ yT,
                const unsigned short* __restrict__ wd,
                const float* __restrict__ g2, const float* __restrict__ b2,
                const float* __restrict__ m2, const float* __restrict__ v2,
                unsigned short* __restrict__ tT) {
  __shared__ float patch[16 * P_GC_STR];         // 41216 B
  __shared__ unsigned short wts[49 * W_TAP_STR]; // 22736 B
  __shared__ unsigned short tb[224 * 16];        // 7168 B
  __shared__ float a2s[16], b2s[16];

  const int tid = threadIdx.x;
  const int st = blockIdx.x;  // 4-row stripe 0..13
  const int g = blockIdx.y;
  const int b = blockIdx.z;
  const int h0 = st * 4;

  // wts: 49 taps x 224 stripe pixels from planar wd
  {
    const unsigned short* wdp =
        wd + (size_t)(g * KK_) * NTOT + (size_t)b * HW_ + h0 * W_;
    for (int idx = tid; idx < KK_ * 28; idx += 256) {
      int tap = idx / 28, ch = idx - tap * 28;
      uint4 v = *(const uint4*)(wdp + (size_t)tap * NTOT + ch * 8);
      *(uint4*)&wts[tap * W_TAP_STR + ch * 8] = v;
    }
    if (tid < 16) {
      int c = g * GC_ + tid;
      float sc = g2[c] * rsqrtf(v2[c] + DEV_EPS);
      a2s[tid] = sc;
      b2s[tid] = b2[c] - m2[c] * sc;
    }
    // patch: 620 positions (10r x 62c), all 16 gc per position from y_T
    for (int e = tid; e < 620; e += 256) {
      int row = e / 62, cw = e - row * 62;
      int sr = h0 + row - 3, sc = cw - 3;
      int off = row * 64 + cw;
      if (sr >= 0 && sr < H_ && sc >= 0 && sc < W_) {
        const unsigned short* yp =
            yT + ((size_t)b * HW_ + sr * W_ + sc) * C_ + g * GC_;
        uint4 v0 = *(const uint4*)yp;
        uint4 v1 = *(const uint4*)(yp + 8);
        unsigned wv[8] = {v0.x, v0.y, v0.z, v0.w, v1.x, v1.y, v1.z, v1.w};
#pragma unroll
        for (int cc = 0; cc < 8; ++cc) {
          patch[(2 * cc) * P_GC_STR + off] = __uint_as_float(wv[cc] << 16);
          patch[(2 * cc + 1) * P_GC_STR + off] =
              __uint_as_float(wv[cc] & 0xffff0000u);
        }
      } else {
#pragma unroll
        for (int cc = 0; cc < 16; ++cc) patch[cc * P_GC_STR + off] = 0.f;
      }
    }
  }
  __syncthreads();

  // compute: item = (px4 strip s, gc); results stashed to tb[px][gc]
#pragma unroll 1
  for (int it = 0; it < 4; ++it) {
    int item = tid + it * 256;
    if (item < 56 * 16) {
      const int gc = item & 15, s = item >> 4;
      const int r0 = s / 14, c0 = (s - r0 * 14) * 4;
      const float* prow0 = patch + gc * P_GC_STR + r0 * 64 + c0;
      const unsigned short* wp = wts + (r0 * 56 + c0);
      float acc0 = 0.f, acc1 = 0.f, acc2 = 0.f, acc3 = 0.f;
#pragma unroll
      for (int di = 0; di < 7; ++di) {
        const float* pr = prow0 + di * 64;
        float4 pa = *(const float4*)pr;
        float4 pb = *(const float4*)(pr + 4);
        float4 pc2 = *(const float4*)(pr + 8);
        float pf[12] = {pa.x, pa.y, pa.z, pa.w, pb.x, pb.y,
                        pb.z, pb.w, pc2.x, pc2.y, pc2.z, pc2.w};
#pragma unroll
        for (int dj = 0; dj < 7; ++dj) {
          ushort4 wv = *(const ushort4*)(wp + (di * 7 + dj) * W_TAP_STR);
          acc0 += bf2f(wv.x) * pf[dj + 0];
          acc1 += bf2f(wv.y) * pf[dj + 1];
          acc2 += bf2f(wv.z) * pf[dj + 2];
          acc3 += bf2f(wv.w) * pf[dj + 3];
        }
      }
      const float al = a2s[gc], be = b2s[gc];
      const int pxb = r0 * 56 + c0;
      tb[(pxb + 0) * 16 + gc] = bf16r(tanhf(al * acc0 + be));
      tb[(pxb + 1) * 16 + gc] = bf16r(tanhf(al * acc1 + be));
      tb[(pxb + 2) * 16 + gc] = bf16r(tanhf(al * acc2 + be));
      tb[(pxb + 3) * 16 + gc] = bf16r(tanhf(al * acc3 + be));
    }
  }
  __syncthreads();

  if (tid < 224) {
    unsigned short* dst = tT + ((size_t)b * HW_ + h0 * W_ + tid) * C_ + g * GC_;
    *(uint4*)(dst + 0) = *(const uint4*)&tb[tid * 16];
    *(uint4*)(dst + 8) = *(const uint4*)&tb[tid * 16 + 8];
  }
}

}  // namespace

extern "C" void kernel_launch(void* const* d_in, const int* in_sizes, int n_in,
                              void* d_out, int out_size, void* d_ws, size_t ws_size,
                              hipStream_t stream) {
  const float* x = (const float*)d_in[0];
  const float* w1 = (const float*)d_in[1];
  const float* b1 = (const float*)d_in[2];
  const float* bn1g = (const float*)d_in[3];
  const float* bn1b = (const float*)d_in[4];
  const float* bn1m = (const float*)d_in[5];
  const float* bn1v = (const float*)d_in[6];
  const float* red_w = (const float*)d_in[7];
  const float* red_b = (const float*)d_in[8];
  const float* rbg = (const float*)d_in[9];
  const float* rbb = (const float*)d_in[10];
  const float* rbm = (const float*)d_in[11];
  const float* rbv = (const float*)d_in[12];
  const float* span_w = (const float*)d_in[13];
  const float* span_b = (const float*)d_in[14];
  const float* bn2g = (const float*)d_in[15];
  const float* bn2b = (const float*)d_in[16];
  const float* bn2m = (const float*)d_in[17];
  const float* bn2v = (const float*)d_in[18];
  const float* w3 = (const float*)d_in[19];
  const float* b3 = (const float*)d_in[20];
  const float* bn3g = (const float*)d_in[21];
  const float* bn3b = (const float*)d_in[22];
  const float* bn3m = (const float*)d_in[23];
  const float* bn3v = (const float*)d_in[24];

  unsigned short* ws = (unsigned short*)d_ws;
  unsigned short* xT = ws;                       // 50176*256
  unsigned short* yT = xT + (size_t)NTOT * C_;   // 50176*256
  unsigned short* rT = yT + (size_t)NTOT * C_;   // 50176*64
  unsigned short* tT = rT + (size_t)NTOT * RED_; // 50176*256
  unsigned short* wd = tT + (size_t)NTOT * C_;   // 784*50176
  unsigned short* w1b = wd + (size_t)784 * NTOT;
  unsigned short* redb = w1b + 65536;
  unsigned short* spanb = redb + 16384;
  unsigned short* w3b = spanb + 50176;
  float* out = (float*)d_out;

  dim3 blk(256);
  wconv<<<dim3(256), blk, 0, stream>>>(w1, red_w, span_w, w3, w1b, redb, spanb, w3b);
  transpose_x<<<dim3(392), blk, 0, stream>>>(x, xT);
  // y_T = tanh(bn1(w1 @ x))
  mfma_gemm<2, 2, 256, 0><<<dim3(392, 2), blk, 0, stream>>>(
      w1b, xT, b1, bn1g, bn1b, bn1m, bn1v, nullptr, yT, C_);
  // r_T = relu(bn_red(red_w @ y))
  mfma_gemm<1, 4, 256, 1><<<dim3(196, 1), blk, 0, stream>>>(
      redb, yT, red_b, rbg, rbb, rbm, rbv, nullptr, rT, RED_);
  // wd = span_w @ r + span_b  (planar bf16 [784][NTOT])
  mfma_gemm<2, 2, 64, 2><<<dim3(392, 7), blk, 0, stream>>>(
      spanb, rT, span_b, nullptr, nullptr, nullptr, nullptr, nullptr, wd, 784);
  // t_T = tanh(bn2(gather(y, wd)))
  gather_inv<<<dim3(14, 16, 16), blk, 0, stream>>>(
      yT, wd, bn2g, bn2b, bn2m, bn2v, tT);
  // out = bn3(w3 @ t) + x  (planar fp32)
  mfma_gemm<2, 2, 256, 3><<<dim3(392, 2), blk, 0, stream>>>(
      w3b, tT, b3, bn3g, bn3b, bn3m, bn3v, x, out, C_);
}

// Round 6
// 356.480 us; speedup vs baseline: 7.2551x; 1.0916x over previous
//
#include <hip/hip_runtime.h>
#include <math.h>

#define DEV_EPS 1e-5f

namespace {
constexpr int B_ = 16, C_ = 256, H_ = 56, W_ = 56, HW_ = H_ * W_;
constexpr int G_ = 16, GC_ = 16, RED_ = 64, KK_ = 49;
constexpr int NTOT = B_ * HW_;  // 50176 flattened (batch, pixel)

typedef __attribute__((ext_vector_type(8))) short short8;
typedef __attribute__((ext_vector_type(4))) float f32x4;

__device__ __forceinline__ unsigned short bf16r(float f) {
  unsigned u = __float_as_uint(f);
  u += 0x7fff + ((u >> 16) & 1);  // RNE
  return (unsigned short)(u >> 16);
}
__device__ __forceinline__ float bf2f(unsigned short s) {
  return __uint_as_float((unsigned)s << 16);
}

// async global->LDS, 16B per lane. LDS dest is wave-uniform base + lane*16
// (m104: no per-lane LDS scatter) — so any swizzle goes on the GLOBAL address.
__device__ __forceinline__ void gl_lds16(const void* g, void* l) {
  __builtin_amdgcn_global_load_lds(
      (const __attribute__((address_space(1))) unsigned int*)g,
      (__attribute__((address_space(3))) unsigned int*)l, 16, 0, 0);
}

// ---------------------------------------------------------------------------
// MFMA GEMM: D[m][n] = sum_k Wt[m][k] * Act[n][k]   (both bf16, k-contiguous)
// Block = 256 threads = 4 waves; wave tile 64x64; BM=WM*64, BN=WN*64, BK=64.
// LDS tiles [row][64k] bf16, 128B rows; global chunk q^(row&7) XOR-swizzle so
// frag ds_read_b128 is 2-way-only (free, m136).
// EPI: 0 = tanh(bn)->act_T bf16, 1 = relu(bn)->act_T bf16,
//      3 = bn + x skip -> planar fp32 [b][C][HW] (final out)
// ---------------------------------------------------------------------------
template <int WM, int WN, int KD, int EPI>
__global__ __launch_bounds__(256)
void mfma_gemm(const unsigned short* __restrict__ A,   // [M][KD] bf16
               const unsigned short* __restrict__ Act, // [NTOT][KD] bf16
               const float* __restrict__ p0,
               const float* __restrict__ bg, const float* __restrict__ bb,
               const float* __restrict__ bm, const float* __restrict__ bv,
               const float* __restrict__ xskip, void* __restrict__ outp,
               int M) {
  constexpr int BM = WM * 64, BN = WN * 64;
  __shared__ unsigned short At[BM * 64];
  __shared__ unsigned short Bt[BN * 64];
  __shared__ float aS[BM], bS[BM];

  const int tid = threadIdx.x;
  const int n0 = blockIdx.x * BN, m0 = blockIdx.y * BM;
  const int wave = tid >> 6, lane = tid & 63;
  const int wm = (WM == 2) ? (wave >> 1) : 0;
  const int wn = (WM == 2) ? (wave & 1) : wave;

  if (tid < BM) {
    int m = min(m0 + tid, M - 1);
    float sc = bg[m] * rsqrtf(bv[m] + DEV_EPS);
    aS[tid] = sc;
    bS[tid] = sc * p0[m] + bb[m] - bm[m] * sc;
  }

  f32x4 acc[4][4];
#pragma unroll
  for (int i = 0; i < 4; ++i)
#pragma unroll
    for (int j = 0; j < 4; ++j)
#pragma unroll
      for (int e = 0; e < 4; ++e) acc[i][j][e] = 0.f;

  const int lq = lane & 7;          // chunk slot within a row-octet
  const int lr8 = lane >> 3;        // row within octet group
  const int quad = lane >> 4, ln = lane & 15;

#pragma unroll 1
  for (int kt = 0; kt < KD / 64; ++kt) {
    __syncthreads();  // protect LDS from previous iteration's readers
    // stage A: BM rows x 64k; one instr = 8 rows (1KB)
#pragma unroll
    for (int t = 0; t < BM / 32; ++t) {
      int inst = wave * (BM / 32) + t;
      int row = inst * 8 + lr8;
      int mrow = min(m0 + row, M - 1);
      int qs = lq ^ (row & 7);
      gl_lds16(A + (size_t)mrow * KD + kt * 64 + qs * 8, &At[inst * 512]);
    }
    // stage B (activations)
#pragma unroll
    for (int t = 0; t < BN / 32; ++t) {
      int inst = wave * (BN / 32) + t;
      int row = inst * 8 + lr8;
      int qs = lq ^ (row & 7);
      gl_lds16(Act + (size_t)(n0 + row) * KD + kt * 64 + qs * 8, &Bt[inst * 512]);
    }
    __syncthreads();  // barrier drains vmcnt -> LDS tiles complete

#pragma unroll
    for (int s = 0; s < 2; ++s) {
      const int c = s * 4 + quad;
      short8 af[4], bf[4];
#pragma unroll
      for (int i = 0; i < 4; ++i) {
        int r = wm * 64 + i * 16 + ln;
        af[i] = *(const short8*)&At[r * 64 + (c ^ (r & 7)) * 8];
      }
#pragma unroll
      for (int j = 0; j < 4; ++j) {
        int r = wn * 64 + j * 16 + ln;
        bf[j] = *(const short8*)&Bt[r * 64 + (c ^ (r & 7)) * 8];
      }
#pragma unroll
      for (int i = 0; i < 4; ++i)
#pragma unroll
        for (int j = 0; j < 4; ++j)
          acc[i][j] = __builtin_amdgcn_mfma_f32_16x16x32_bf16(af[i], bf[j],
                                                              acc[i][j], 0, 0, 0);
    }
  }

  // epilogue: D col = lane&15 (n), row = quad*4 + reg (m)  [m89-verified]
#pragma unroll
  for (int i = 0; i < 4; ++i) {
    const int mloc = wm * 64 + i * 16 + quad * 4;
#pragma unroll
    for (int j = 0; j < 4; ++j) {
      const int np = n0 + wn * 64 + j * 16 + ln;
      if (EPI == 0 || EPI == 1) {
        ushort4 pk;
        unsigned short* pp = (unsigned short*)&pk;
#pragma unroll
        for (int r = 0; r < 4; ++r) {
          float v = aS[mloc + r] * acc[i][j][r] + bS[mloc + r];
          v = (EPI == 0) ? tanhf(v) : fmaxf(v, 0.f);
          pp[r] = bf16r(v);
        }
        *(ushort4*)((unsigned short*)outp + (size_t)np * M + m0 + mloc) = pk;
      } else {
        int b = np / HW_, hw = np - b * HW_;
        size_t base = ((size_t)b * C_ + m0 + mloc) * HW_ + hw;
#pragma unroll
        for (int r = 0; r < 4; ++r) {
          size_t o = base + (size_t)r * HW_;
          ((float*)outp)[o] =
              aS[mloc + r] * acc[i][j][r] + bS[mloc + r] + xskip[o];
        }
      }
    }
  }
}

// ---------------------------------------------------------------------------
// x (planar fp32) -> x_T (bf16, [b*HW+px][c])  via LDS transpose.
// ---------------------------------------------------------------------------
__global__ __launch_bounds__(256)
void transpose_x(const float* __restrict__ x, unsigned short* __restrict__ xT) {
  __shared__ unsigned short tile[128 * 72];
  const int tid = threadIdx.x;
  const int px0 = blockIdx.x * 128;
  for (int p = 0; p < 4; ++p) {
    if (p) __syncthreads();
#pragma unroll
    for (int e = 0; e < 32; ++e) {
      int flat = e * 256 + tid;
      int cl = flat >> 7, pxl = flat & 127;
      int px = px0 + pxl;
      int b = px / HW_, hw = px - b * HW_;
      tile[pxl * 72 + cl] = bf16r(x[((size_t)b * C_ + p * 64 + cl) * HW_ + hw]);
    }
    __syncthreads();
    int px = tid >> 1, half = tid & 1;
    const unsigned short* src = &tile[px * 72 + half * 32];
    unsigned short* dst = &xT[(size_t)(px0 + px) * C_ + p * 64 + half * 32];
    *(uint4*)(dst + 0) = *(const uint4*)(src + 0);
    *(uint4*)(dst + 8) = *(const uint4*)(src + 8);
    *(uint4*)(dst + 16) = *(const uint4*)(src + 16);
    *(uint4*)(dst + 24) = *(const uint4*)(src + 24);
  }
}

// weights fp32 -> bf16 (all four mats)
__global__ __launch_bounds__(256)
void wconv(const float* __restrict__ w1, const float* __restrict__ rw,
           const float* __restrict__ sw, const float* __restrict__ w3,
           unsigned short* __restrict__ o1, unsigned short* __restrict__ orw,
           unsigned short* __restrict__ osw, unsigned short* __restrict__ ow3) {
  int i = blockIdx.x * 256 + threadIdx.x;
  if (i < 65536) o1[i] = bf16r(w1[i]);
  if (i < 16384) orw[i] = bf16r(rw[i]);
  if (i < 50176) osw[i] = bf16r(sw[i]);
  if (i < 65536) ow3[i] = bf16r(w3[i]);
}

// ---------------------------------------------------------------------------
// Gather v5: span GEMM FUSED in (kills the 157 MB wd HBM round-trip).
// Per block (b, g, 4-row stripe):
//   phase 0: stage patch (y_T -> fp32 planes), rs (r_T stripe, bf16 swizzled),
//            sws (span_w g-slice, bf16 swizzled), params.
//   phase 1: mini-MFMA  wts[49x224] = sws(49x64) @ rs(224x64)^T + span_b.
//            Wave w owns taps w*16..w*16+15; 14 n-tiles x 2 k-steps = 28 MFMA.
//   phase 2: write wts (bf16) into LDS aliasing rs/sws.
//   phase 3: 7x7 gather + bn2 + tanh (round-4/5 proven code), tb bounce,
//            coalesced t_T store.
// LDS: patch 41216 + union(rs+sws 36864 | wts 22736 + tb 7168) + params
//      = ~78.4 KB -> 2 blocks/CU.
// ---------------------------------------------------------------------------
constexpr int P_GC_STR = 644;   // fp32 plane: 10r*64c + 4 pad
constexpr int W_TAP_STR = 232;  // ushort: 224 px + 8 pad

__global__ __launch_bounds__(256)
void gather_inv(const unsigned short* __restrict__ yT,
                const unsigned short* __restrict__ rT,
                const unsigned short* __restrict__ spanw,  // [784][64] bf16
                const float* __restrict__ spanb,           // [784] fp32
                const float* __restrict__ g2, const float* __restrict__ b2,
                const float* __restrict__ m2, const float* __restrict__ v2,
                unsigned short* __restrict__ tT) {
  __shared__ float patch[16 * P_GC_STR];            // 41216 B
  __shared__ __align__(16) unsigned short reg2[18432];  // 36864 B union
  __shared__ float a2s[16], b2s[16], sbs[KK_];

  unsigned short* rs = reg2;           // 224*64 shorts (swizzled rows)
  unsigned short* sws = reg2 + 14336;  // 64*64 shorts (swizzled rows)
  unsigned short* wts = reg2;                    // aliases after phase 1
  unsigned short* tb = reg2 + KK_ * W_TAP_STR;   // 224*16 shorts

  const int tid = threadIdx.x;
  const int st = blockIdx.x;  // 4-row stripe 0..13
  const int g = blockIdx.y;
  const int b = blockIdx.z;
  const int h0 = st * 4;
  const int wave = tid >> 6, lane = tid & 63;
  const int lq = lane & 7, lr8 = lane >> 3;
  const int quad = lane >> 4, ln = lane & 15;

  // ---- phase 0: staging ----
  {
    // rs: 224 rows (stripe pixels) x 64k bf16, XOR-swizzled chunks
    const unsigned short* rbase = rT + ((size_t)b * HW_ + h0 * W_) * RED_;
#pragma unroll
    for (int t = 0; t < 7; ++t) {
      int inst = wave * 7 + t;
      int row = inst * 8 + lr8;
      int qs = lq ^ (row & 7);
      gl_lds16(rbase + (size_t)row * RED_ + qs * 8, &rs[inst * 512]);
    }
    // sws: 64 rows (taps, clamped at 48) x 64k
    const unsigned short* swg = spanw + (size_t)(g * KK_) * RED_;
#pragma unroll
    for (int t = 0; t < 2; ++t) {
      int inst = wave * 2 + t;
      int row = inst * 8 + lr8;
      int tap = min(row, KK_ - 1);
      int qs = lq ^ (row & 7);
      gl_lds16(swg + (size_t)tap * RED_ + qs * 8, &sws[inst * 512]);
    }
    if (tid < 16) {
      int c = g * GC_ + tid;
      float sc = g2[c] * rsqrtf(v2[c] + DEV_EPS);
      a2s[tid] = sc;
      b2s[tid] = b2[c] - m2[c] * sc;
    }
    if (tid < KK_) sbs[tid] = spanb[g * KK_ + tid];
    // patch: 620 positions (10r x 62c), all 16 gc per position from y_T
    for (int e = tid; e < 620; e += 256) {
      int row = e / 62, cw = e - row * 62;
      int sr = h0 + row - 3, sc = cw - 3;
      int off = row * 64 + cw;
      if (sr >= 0 && sr < H_ && sc >= 0 && sc < W_) {
        const unsigned short* yp =
            yT + ((size_t)b * HW_ + sr * W_ + sc) * C_ + g * GC_;
        uint4 v0 = *(const uint4*)yp;
        uint4 v1 = *(const uint4*)(yp + 8);
        unsigned wv[8] = {v0.x, v0.y, v0.z, v0.w, v1.x, v1.y, v1.z, v1.w};
#pragma unroll
        for (int cc = 0; cc < 8; ++cc) {
          patch[(2 * cc) * P_GC_STR + off] = __uint_as_float(wv[cc] << 16);
          patch[(2 * cc + 1) * P_GC_STR + off] =
              __uint_as_float(wv[cc] & 0xffff0000u);
        }
      } else {
#pragma unroll
        for (int cc = 0; cc < 16; ++cc) patch[cc * P_GC_STR + off] = 0.f;
      }
    }
  }
  __syncthreads();  // drains vmcnt (global_load_lds) + patch writes

  // ---- phase 1: mini-MFMA  (wave = tap-tile) ----
  f32x4 wacc[14];
#pragma unroll
  for (int j = 0; j < 14; ++j)
#pragma unroll
    for (int e = 0; e < 4; ++e) wacc[j][e] = 0.f;
  {
    short8 af[2];
#pragma unroll
    for (int s = 0; s < 2; ++s) {
      int c = s * 4 + quad;
      int r = wave * 16 + ln;
      af[s] = *(const short8*)&sws[r * 64 + (c ^ (r & 7)) * 8];
    }
#pragma unroll
    for (int j = 0; j < 14; ++j) {
#pragma unroll
      for (int s = 0; s < 2; ++s) {
        int c = s * 4 + quad;
        int r = j * 16 + ln;
        short8 bf = *(const short8*)&rs[r * 64 + (c ^ (r & 7)) * 8];
        wacc[j] = __builtin_amdgcn_mfma_f32_16x16x32_bf16(af[s], bf, wacc[j],
                                                          0, 0, 0);
      }
    }
  }
  __syncthreads();  // all frag reads done; rs/sws region now dead

  // ---- phase 2: write wts[tap][px] bf16 (D: col=ln -> px, row=quad*4+r) ----
  {
#pragma unroll
    for (int r = 0; r < 4; ++r) {
      int tap = wave * 16 + quad * 4 + r;
      if (tap < KK_) {
        float sb = sbs[tap];
#pragma unroll
        for (int j = 0; j < 14; ++j)
          wts[tap * W_TAP_STR + j * 16 + ln] = bf16r(wacc[j][r] + sb);
      }
    }
  }
  __syncthreads();

  // ---- phase 3: 7x7 gather; item = (px4 strip s, gc) ----
#pragma unroll 1
  for (int it = 0; it < 4; ++it) {
    int item = tid + it * 256;
    if (item < 56 * 16) {
      const int gc = item & 15, s = item >> 4;
      const int r0 = s / 14, c0 = (s - r0 * 14) * 4;
      const float* prow0 = patch + gc * P_GC_STR + r0 * 64 + c0;
      const unsigned short* wp = wts + (r0 * 56 + c0);
      float acc0 = 0.f, acc1 = 0.f, acc2 = 0.f, acc3 = 0.f;
#pragma unroll
      for (int di = 0; di < 7; ++di) {
        const float* pr = prow0 + di * 64;
        float4 pa = *(const float4*)pr;
        float4 pb = *(const float4*)(pr + 4);
        float4 pc2 = *(const float4*)(pr + 8);
        float pf[12] = {pa.x, pa.y, pa.z, pa.w, pb.x, pb.y,
                        pb.z, pb.w, pc2.x, pc2.y, pc2.z, pc2.w};
#pragma unroll
        for (int dj = 0; dj < 7; ++dj) {
          ushort4 wv = *(const ushort4*)(wp + (di * 7 + dj) * W_TAP_STR);
          acc0 += bf2f(wv.x) * pf[dj + 0];
          acc1 += bf2f(wv.y) * pf[dj + 1];
          acc2 += bf2f(wv.z) * pf[dj + 2];
          acc3 += bf2f(wv.w) * pf[dj + 3];
        }
      }
      const float al = a2s[gc], be = b2s[gc];
      const int pxb = r0 * 56 + c0;
      tb[(pxb + 0) * 16 + gc] = bf16r(tanhf(al * acc0 + be));
      tb[(pxb + 1) * 16 + gc] = bf16r(tanhf(al * acc1 + be));
      tb[(pxb + 2) * 16 + gc] = bf16r(tanhf(al * acc2 + be));
      tb[(pxb + 3) * 16 + gc] = bf16r(tanhf(al * acc3 + be));
    }
  }
  __syncthreads();

  if (tid < 224) {
    unsigned short* dst = tT + ((size_t)b * HW_ + h0 * W_ + tid) * C_ + g * GC_;
    *(uint4*)(dst + 0) = *(const uint4*)&tb[tid * 16];
    *(uint4*)(dst + 8) = *(const uint4*)&tb[tid * 16 + 8];
  }
}

}  // namespace

extern "C" void kernel_launch(void* const* d_in, const int* in_sizes, int n_in,
                              void* d_out, int out_size, void* d_ws, size_t ws_size,
                              hipStream_t stream) {
  const float* x = (const float*)d_in[0];
  const float* w1 = (const float*)d_in[1];
  const float* b1 = (const float*)d_in[2];
  const float* bn1g = (const float*)d_in[3];
  const float* bn1b = (const float*)d_in[4];
  const float* bn1m = (const float*)d_in[5];
  const float* bn1v = (const float*)d_in[6];
  const float* red_w = (const float*)d_in[7];
  const float* red_b = (const float*)d_in[8];
  const float* rbg = (const float*)d_in[9];
  const float* rbb = (const float*)d_in[10];
  const float* rbm = (const float*)d_in[11];
  const float* rbv = (const float*)d_in[12];
  const float* span_w = (const float*)d_in[13];
  const float* span_b = (const float*)d_in[14];
  const float* bn2g = (const float*)d_in[15];
  const float* bn2b = (const float*)d_in[16];
  const float* bn2m = (const float*)d_in[17];
  const float* bn2v = (const float*)d_in[18];
  const float* w3 = (const float*)d_in[19];
  const float* b3 = (const float*)d_in[20];
  const float* bn3g = (const float*)d_in[21];
  const float* bn3b = (const float*)d_in[22];
  const float* bn3m = (const float*)d_in[23];
  const float* bn3v = (const float*)d_in[24];

  unsigned short* ws = (unsigned short*)d_ws;
  unsigned short* xT = ws;                       // 50176*256
  unsigned short* yT = xT + (size_t)NTOT * C_;   // 50176*256
  unsigned short* rT = yT + (size_t)NTOT * C_;   // 50176*64
  unsigned short* tT = rT + (size_t)NTOT * RED_; // 50176*256
  unsigned short* w1b = tT + (size_t)NTOT * C_;
  unsigned short* redb = w1b + 65536;
  unsigned short* spanb = redb + 16384;
  unsigned short* w3b = spanb + 50176;
  float* out = (float*)d_out;

  dim3 blk(256);
  wconv<<<dim3(256), blk, 0, stream>>>(w1, red_w, span_w, w3, w1b, redb, spanb, w3b);
  transpose_x<<<dim3(392), blk, 0, stream>>>(x, xT);
  // y_T = tanh(bn1(w1 @ x))
  mfma_gemm<2, 2, 256, 0><<<dim3(392, 2), blk, 0, stream>>>(
      w1b, xT, b1, bn1g, bn1b, bn1m, bn1v, nullptr, yT, C_);
  // r_T = relu(bn_red(red_w @ y))
  mfma_gemm<1, 4, 256, 1><<<dim3(196, 1), blk, 0, stream>>>(
      redb, yT, red_b, rbg, rbb, rbm, rbv, nullptr, rT, RED_);
  // t_T = tanh(bn2(involution(y; span(r))))  — span fused in
  gather_inv<<<dim3(14, 16, 16), blk, 0, stream>>>(
      yT, rT, spanb, span_b, bn2g, bn2b, bn2m, bn2v, tT);
  // out = bn3(w3 @ t) + x  (planar fp32)
  mfma_gemm<2, 2, 256, 3><<<dim3(392, 2), blk, 0, stream>>>(
      w3b, tT, b3, bn3g, bn3b, bn3m, bn3v, x, out, C_);
}